// Round 1
// baseline (463.937 us; speedup 1.0000x reference)
//
#include <hip/hip_runtime.h>
#include <stdint.h>

#define N_IT 10000
#define DH 128
#define C2 256
#define C3 384
#define BATCH 1024
#define HIST 100
#define NT_PAD 10032
#define MB_I 157   // ceil(10000/64)

typedef __attribute__((ext_vector_type(4))) float f32x4;
typedef __attribute__((ext_vector_type(8))) short s16x8;

__device__ __forceinline__ unsigned short f2b(float x){
    union { float f; uint32_t u; } v; v.f = x;
    uint32_t r = (v.u + 0x7FFF + ((v.u >> 16) & 1)) >> 16;
    return (unsigned short)r;
}
__device__ __forceinline__ float b2f(unsigned short u){
    union { uint32_t u; float f; } v; v.u = ((uint32_t)u) << 16;
    return v.f;
}

// ---------------- prep: bf16 copies ----------------
__global__ void prep_kernel(const float* __restrict__ emb_in, const float* __restrict__ emb_out,
                            const float* __restrict__ Wq, const float* __restrict__ Wk,
                            const float* __restrict__ Wv,
                            unsigned short* __restrict__ Qbf, unsigned short* __restrict__ QbfT,
                            unsigned short* __restrict__ WqB, unsigned short* __restrict__ WkB,
                            unsigned short* __restrict__ WvTB)
{
    int idx = blockIdx.x * 256 + threadIdx.x;
    const int nQ = N_IT * C2;
    const int nT = C2 * NT_PAD;
    const int nW = C3 * C3;
    if (idx < nQ) {
        int i = idx >> 8, c = idx & 255;
        float v = (c < DH) ? emb_in[i*DH + c] : emb_out[i*DH + (c-DH)];
        Qbf[idx] = f2b(v);
    } else if (idx < nQ + nT) {
        int t = idx - nQ;
        int c = t / NT_PAD, j = t % NT_PAD;
        float v = 0.f;
        if (j < N_IT) v = (c < DH) ? emb_in[j*DH + c] : emb_out[j*DH + (c-DH)];
        QbfT[t] = f2b(v);
    } else if (idx < nQ + nT + 3*nW) {
        int t = idx - nQ - nT;
        int m = t / nW, r = t % nW;
        if (m == 0) WqB[r] = f2b(Wq[r]);
        else if (m == 1) WkB[r] = f2b(Wk[r]);
        else { int d = r / C3, e = r % C3; WvTB[e*C3 + d] = f2b(Wv[r]); }
    }
}

// ---------------- region: flash softmax(QK^T/16)@Q ----------------
__global__ __launch_bounds__(256, 2) void region_kernel(
    const unsigned short* __restrict__ Qbf, const unsigned short* __restrict__ QbfT,
    float* __restrict__ Rpart, float* __restrict__ rspart, int J)
{
    __shared__ __align__(16) unsigned short QjL[32*256];   // 16KB, swizzled 512B rows
    __shared__ __align__(16) unsigned short QjTL[256*40];  // 20KB, 80B rows (pad)
    __shared__ __align__(16) unsigned short PL[4*16*40];   // 5KB per-wave P

    int tid = threadIdx.x;
    int w = tid >> 6, l = tid & 63;
    int lm = l & 15, lq = l >> 4;

    int ib = blockIdx.x / J;
    int split = blockIdx.x % J;
    int chunk = (N_IT + J - 1) / J;
    int jbeg = split * chunk;
    int jend = min(jbeg + chunk, N_IT);

    int i0 = ib * 64;
    int irow = i0 + w*16 + lm;
    int irc = min(irow, N_IT-1);

    s16x8 qa[8];
    #pragma unroll
    for (int kk = 0; kk < 8; kk++)
        qa[kk] = *(const s16x8*)(Qbf + irc*C2 + (lq*8 + 32*kk));

    f32x4 racc[16];
    #pragma unroll
    for (int nt = 0; nt < 16; nt++) racc[nt] = (f32x4){0,0,0,0};
    float rs[4] = {0.f,0.f,0.f,0.f};

    for (int j0 = jbeg; j0 < jend; j0 += 32) {
        #pragma unroll
        for (int c = 0; c < 4; c++) {           // stage Qj rows (swizzled)
            int ch = tid + c*256;
            int r = ch >> 5, ci = ch & 31;
            int sr = min(j0 + r, N_IT-1);
            s16x8 v = *(const s16x8*)(Qbf + sr*C2 + ci*8);
            *(s16x8*)((char*)QjL + r*512 + ((ci*16) ^ ((r&7)<<4))) = v;
        }
        #pragma unroll
        for (int c = 0; c < 4; c++) {           // stage QjT cols (padded rows)
            int ch = tid + c*256;
            int r = ch >> 2, ci = ch & 3;
            s16x8 v = *(const s16x8*)(QbfT + (size_t)r*NT_PAD + j0 + ci*8);
            *(s16x8*)((char*)QjTL + r*80 + ci*16) = v;
        }
        __syncthreads();

        #pragma unroll
        for (int jt = 0; jt < 2; jt++) {
            f32x4 sacc = (f32x4){0,0,0,0};
            int jr = jt*16 + lm;
            #pragma unroll
            for (int kk = 0; kk < 8; kk++) {
                int elem = (lq*8 + 32*kk) ^ 128;   // K = half-swapped Q
                s16x8 bf = *(const s16x8*)((char*)QjL + jr*512 + ((2*elem) ^ ((jr&7)<<4)));
                sacc = __builtin_amdgcn_mfma_f32_16x16x32_bf16(qa[kk], bf, sacc, 0,0,0);
            }
            int jcol = j0 + jt*16 + lm;
            #pragma unroll
            for (int r = 0; r < 4; r++) {
                float e = 0.f;
                if (jcol < jend) e = __expf(sacc[r] * 0.0625f);
                rs[r] += e;
                *(unsigned short*)((char*)PL + (w*16 + lq*4 + r)*80 + 2*(jt*16 + lm)) = f2b(e);
            }
        }
        s16x8 a2 = *(const s16x8*)((char*)PL + (w*16 + lm)*80 + 16*lq);
        #pragma unroll
        for (int nt = 0; nt < 16; nt++) {
            s16x8 bf = *(const s16x8*)((char*)QjTL + (nt*16 + lm)*80 + 16*lq);
            racc[nt] = __builtin_amdgcn_mfma_f32_16x16x32_bf16(a2, bf, racc[nt], 0,0,0);
        }
        __syncthreads();
    }

    #pragma unroll
    for (int r = 0; r < 4; r++) {
        float v = rs[r];
        v += __shfl_xor(v, 1); v += __shfl_xor(v, 2);
        v += __shfl_xor(v, 4); v += __shfl_xor(v, 8);
        rs[r] = v;
    }
    if (lm == 0) {
        #pragma unroll
        for (int r = 0; r < 4; r++) {
            int gi = i0 + w*16 + lq*4 + r;
            if (gi < N_IT) rspart[split*N_IT + gi] = rs[r];
        }
    }
    #pragma unroll
    for (int nt = 0; nt < 16; nt++)
        #pragma unroll
        for (int r = 0; r < 4; r++) {
            int gi = i0 + w*16 + lq*4 + r;
            if (gi < N_IT)
                Rpart[((size_t)split*N_IT + gi)*C2 + nt*16 + lm] = racc[nt][r];
        }
}

// ---------------- combine partials -> region f32 + Hsrc bf16 ----------------
__global__ void combine_kernel(const float* __restrict__ Rpart, const float* __restrict__ rspart,
                               const float* __restrict__ emb_item,
                               float* __restrict__ region, unsigned short* __restrict__ Hsrc, int J)
{
    int idx = blockIdx.x * 256 + threadIdx.x;
    if (idx >= N_IT * C3) return;
    int i = idx / C3, c = idx % C3;
    if (c < DH) {
        Hsrc[(size_t)i*C3 + c] = f2b(emb_item[i*DH + c]);
    } else {
        int cc = c - DH;
        float s = 0.f, d = 0.f;
        for (int sp = 0; sp < J; sp++) {
            s += Rpart[((size_t)sp*N_IT + i)*C2 + cc];
            d += rspart[sp*N_IT + i];
        }
        float v = s / d;
        region[(size_t)i*C2 + cc] = v;
        Hsrc[(size_t)i*C3 + c] = f2b(v);
    }
}

// ---------------- targets + c = bv.tgt ----------------
__global__ void tgt_kernel(const int* __restrict__ item_i, const int* __restrict__ item_j,
                           const float* __restrict__ emb_item, const float* __restrict__ region,
                           const float* __restrict__ bv,
                           unsigned short* __restrict__ TpB, unsigned short* __restrict__ TnB,
                           float* __restrict__ cpn)
{
    __shared__ float red[4];
    int b = blockIdx.x;
    int tid = threadIdx.x;   // 128
    int ii = item_i[b], jj = item_j[b];
    float cp = 0.f, cn = 0.f;
    for (int e = tid; e < C3; e += 128) {
        float vp = (e < DH) ? emb_item[ii*DH + e] : region[ii*C2 + (e-DH)];
        float vn = (e < DH) ? emb_item[jj*DH + e] : region[jj*C2 + (e-DH)];
        TpB[(size_t)b*C3 + e] = f2b(vp);
        TnB[(size_t)b*C3 + e] = f2b(vn);
        float bb = bv[e];
        cp += bb * vp; cn += bb * vn;
    }
    for (int d = 32; d >= 1; d >>= 1) { cp += __shfl_down(cp, d); cn += __shfl_down(cn, d); }
    int wv = tid >> 6;
    if ((tid & 63) == 0) { red[wv] = cp; red[2 + wv] = cn; }
    __syncthreads();
    if (tid == 0) {
        cpn[b] = red[0] + red[1];
        cpn[BATCH + b] = red[2] + red[3];
    }
}

// ---------------- q/g GEMMs: Qp,Qn = T@Wq^T + bq ; Gp,Gn = T@Wv ----------------
__global__ __launch_bounds__(256, 2) void qg_kernel(
    const unsigned short* __restrict__ TpB, const unsigned short* __restrict__ TnB,
    const unsigned short* __restrict__ WqB, const unsigned short* __restrict__ WvTB,
    const float* __restrict__ bq,
    float* __restrict__ Qp, float* __restrict__ Qn,
    float* __restrict__ Gp, float* __restrict__ Gn)
{
    __shared__ __align__(16) unsigned short As[64*C3];  // 48KB swizzled
    int tid = threadIdx.x;
    int gemm = blockIdx.x & 3;
    int bm = blockIdx.x >> 2;

    const unsigned short* A = (gemm == 0 || gemm == 2) ? TpB : TnB;
    const unsigned short* Bm = (gemm < 2) ? WqB : WvTB;
    float* Out = (gemm == 0) ? Qp : (gemm == 1) ? Qn : (gemm == 2) ? Gp : Gn;
    bool addb = (gemm < 2);

    for (int ch = tid; ch < 64*48; ch += 256) {
        int r = ch / 48, ci = ch % 48;
        s16x8 v = *(const s16x8*)(A + (size_t)(bm*64 + r)*C3 + ci*8);
        *(s16x8*)((char*)As + r*768 + ((ci*16) ^ ((r&7)<<4))) = v;
    }
    __syncthreads();

    int w = tid >> 6, l = tid & 63, lm = l & 15, lq = l >> 4;
    f32x4 acc[6][4];
    #pragma unroll
    for (int j = 0; j < 6; j++)
        #pragma unroll
        for (int m = 0; m < 4; m++) acc[j][m] = (f32x4){0,0,0,0};

    for (int kk = 0; kk < 12; kk++) {
        s16x8 a[4];
        #pragma unroll
        for (int m = 0; m < 4; m++) {
            int r = m*16 + lm;
            a[m] = *(const s16x8*)((char*)As + r*768 + ((64*kk + 16*lq) ^ ((r&7)<<4)));
        }
        #pragma unroll
        for (int j = 0; j < 6; j++) {
            int n = (w*6 + j)*16 + lm;
            s16x8 bf = *(const s16x8*)(Bm + (size_t)n*C3 + kk*32 + lq*8);
            #pragma unroll
            for (int m = 0; m < 4; m++)
                acc[j][m] = __builtin_amdgcn_mfma_f32_16x16x32_bf16(a[m], bf, acc[j][m], 0,0,0);
        }
    }
    #pragma unroll
    for (int j = 0; j < 6; j++) {
        int col = (w*6 + j)*16 + lm;
        float bias = addb ? bq[col] : 0.f;
        #pragma unroll
        for (int m = 0; m < 4; m++)
            #pragma unroll
            for (int r = 0; r < 4; r++) {
                int row = bm*64 + m*16 + lq*4 + r;
                Out[(size_t)row*C3 + col] = acc[j][m][r] + bias;
            }
    }
}

// ---------------- per-batch: gather H, key GEMM, weights, preds ----------------
__global__ __launch_bounds__(256, 1) void batch_kernel(
    const int* __restrict__ user, const int* __restrict__ item_i,
    const unsigned short* __restrict__ Hsrc, const unsigned short* __restrict__ WkB,
    const float* __restrict__ bk,
    const float* __restrict__ Qp, const float* __restrict__ Qn,
    const float* __restrict__ Gp, const float* __restrict__ Gn,
    const float* __restrict__ cpn, float* __restrict__ out)
{
    __shared__ __align__(16) unsigned short Hs[HIST*C3]; // 76.8KB swizzled
    __shared__ __align__(16) unsigned short Ks[HIST*C3]; // 76.8KB flat [100][384]
    __shared__ int userL[HIST];
    __shared__ float qpL[C3], qnL[C3], eA[HIST], eB[HIST], hp[C3], hn[C3];
    __shared__ float red[8], scal[2];

    int b = blockIdx.x;
    int tid = threadIdx.x;

    if (tid < HIST) userL[tid] = user[b*HIST + tid];
    for (int e = tid; e < C3; e += 256) { qpL[e] = Qp[(size_t)b*C3+e]; qnL[e] = Qn[(size_t)b*C3+e]; }
    __syncthreads();

    for (int ch = tid; ch < HIST*48; ch += 256) {
        int r = ch / 48, ci = ch % 48;
        s16x8 v = *(const s16x8*)(Hsrc + (size_t)userL[r]*C3 + ci*8);
        *(s16x8*)((char*)Hs + r*768 + ((ci*16) ^ ((r&7)<<4))) = v;
    }
    __syncthreads();

    int w = tid >> 6, l = tid & 63, lm = l & 15, lq = l >> 4;
    {
        f32x4 acc[6][7];
        #pragma unroll
        for (int j = 0; j < 6; j++)
            #pragma unroll
            for (int m = 0; m < 7; m++) acc[j][m] = (f32x4){0,0,0,0};
        for (int kk = 0; kk < 12; kk++) {
            s16x8 a[7];
            #pragma unroll
            for (int m = 0; m < 7; m++) {
                int r = min(m*16 + lm, HIST-1);
                a[m] = *(const s16x8*)((char*)Hs + r*768 + ((64*kk + 16*lq) ^ ((r&7)<<4)));
            }
            #pragma unroll
            for (int j = 0; j < 6; j++) {
                int d = (w*6 + j)*16 + lm;
                s16x8 bf = *(const s16x8*)(WkB + (size_t)d*C3 + kk*32 + lq*8);
                #pragma unroll
                for (int m = 0; m < 7; m++)
                    acc[j][m] = __builtin_amdgcn_mfma_f32_16x16x32_bf16(a[m], bf, acc[j][m], 0,0,0);
            }
        }
        #pragma unroll
        for (int j = 0; j < 6; j++) {
            int d = (w*6 + j)*16 + lm;
            float bias = bk[d];
            #pragma unroll
            for (int m = 0; m < 7; m++)
                #pragma unroll
                for (int r = 0; r < 4; r++) {
                    int row = m*16 + lq*4 + r;
                    if (row < HIST) Ks[row*C3 + d] = f2b(acc[j][m][r] + bias);
                }
        }
    }
    __syncthreads();

    if (tid < HIST) {
        int ii = item_i[b];
        float sp = 0.f, sn = 0.f;
        for (int d = 0; d < C3; d++) {
            float kv = b2f(Ks[d*HIST + tid]);   // flat reshape quirk: K.flat[d*100+l]
            sp += qpL[d] * kv; sn += qnL[d] * kv;
        }
        const float inv_s3 = 0.05103103630798287f;  // 1/sqrt(384)
        sp *= inv_s3; sn *= inv_s3;
        float m = (userL[tid] != ii) ? 1.f : 0.f;
        eA[tid] = __expf(sp) * m;
        eB[tid] = __expf(sn);
    }
    __syncthreads();
    if (tid < 2) {
        const float* e = (tid == 0) ? eA : eB;
        float s = 0.f;
        for (int l2 = 0; l2 < HIST; l2++) s += e[l2];
        scal[tid] = sqrtf(s);   // den = S^0.5 ; also Sum(w) = den
    }
    __syncthreads();

    float invA = 1.f / scal[0], invB = 1.f / scal[1];
    for (int e = tid; e < C3; e += 256) {
        float ap = 0.f, an = 0.f;
        int byte = 2*e;
        int bhi = byte & ~15, blo = byte & 15;
        for (int l2 = 0; l2 < HIST; l2++) {
            float hv = b2f(*(const unsigned short*)((char*)Hs + l2*768 + (bhi ^ ((l2&7)<<4)) + blo));
            ap += eA[l2] * hv; an += eB[l2] * hv;
        }
        hp[e] = ap * invA; hn[e] = an * invB;
    }
    __syncthreads();

    float pi = 0.f, pj = 0.f;
    for (int e = tid; e < C3; e += 256) {
        pi += hp[e] * Gp[(size_t)b*C3 + e];
        pj += hn[e] * Gn[(size_t)b*C3 + e];
    }
    for (int d = 32; d >= 1; d >>= 1) { pi += __shfl_down(pi, d); pj += __shfl_down(pj, d); }
    if (l == 0) { red[w] = pi; red[4 + w] = pj; }
    __syncthreads();
    if (tid == 0) {
        out[b]         = red[0]+red[1]+red[2]+red[3] + scal[0]*cpn[b];
        out[BATCH + b] = red[4]+red[5]+red[6]+red[7] + scal[1]*cpn[BATCH + b];
    }
}

extern "C" void kernel_launch(void* const* d_in, const int* in_sizes, int n_in,
                              void* d_out, int out_size, void* d_ws, size_t ws_size,
                              hipStream_t stream)
{
    const int*   user     = (const int*)d_in[0];
    const int*   item_i   = (const int*)d_in[1];
    const int*   item_j   = (const int*)d_in[2];
    const float* emb_item = (const float*)d_in[3];
    const float* emb_in   = (const float*)d_in[4];
    const float* emb_out  = (const float*)d_in[5];
    const float* Wq = (const float*)d_in[6];
    const float* bq = (const float*)d_in[7];
    const float* Wk = (const float*)d_in[8];
    const float* bk = (const float*)d_in[9];
    const float* Wv = (const float*)d_in[10];
    const float* bv = (const float*)d_in[11];
    float* out = (float*)d_out;

    char* ws = (char*)d_ws;
    size_t off = 0;
    auto alloc = [&](size_t bytes) -> char* {
        char* p = ws + off;
        off = (off + bytes + 255) & ~(size_t)255;
        return p;
    };

    float* region          = (float*)alloc((size_t)N_IT*C2*4);
    unsigned short* Qbf    = (unsigned short*)alloc((size_t)N_IT*C2*2);
    unsigned short* QbfT   = (unsigned short*)alloc((size_t)C2*NT_PAD*2);
    unsigned short* Hsrc   = (unsigned short*)alloc((size_t)N_IT*C3*2);
    unsigned short* WqB    = (unsigned short*)alloc((size_t)C3*C3*2);
    unsigned short* WkB    = (unsigned short*)alloc((size_t)C3*C3*2);
    unsigned short* WvTB   = (unsigned short*)alloc((size_t)C3*C3*2);
    unsigned short* TpB    = (unsigned short*)alloc((size_t)BATCH*C3*2);
    unsigned short* TnB    = (unsigned short*)alloc((size_t)BATCH*C3*2);
    float* Qp              = (float*)alloc((size_t)BATCH*C3*4);
    float* Qn              = (float*)alloc((size_t)BATCH*C3*4);
    float* Gp              = (float*)alloc((size_t)BATCH*C3*4);
    float* Gn              = (float*)alloc((size_t)BATCH*C3*4);
    float* cpn             = (float*)alloc((size_t)2*BATCH*4);

    size_t fixed_bytes = off;
    size_t per_split = ((size_t)N_IT*C2*4 + 256) + ((size_t)N_IT*4 + 256);
    int J = 4;
    if (ws_size < fixed_bytes + 4*per_split) J = 2;
    if (ws_size < fixed_bytes + 2*per_split) J = 1;

    float* Rpart  = (float*)alloc((size_t)J*N_IT*C2*4);
    float* rspart = (float*)alloc((size_t)J*N_IT*4);

    // 1) prep
    {
        int total = N_IT*C2 + C2*NT_PAD + 3*C3*C3;
        int blocks = (total + 255) / 256;
        prep_kernel<<<blocks, 256, 0, stream>>>(emb_in, emb_out, Wq, Wk, Wv,
                                                Qbf, QbfT, WqB, WkB, WvTB);
    }
    // 2) region partials
    region_kernel<<<MB_I * J, 256, 0, stream>>>(Qbf, QbfT, Rpart, rspart, J);
    // 3) combine -> region f32 + Hsrc bf16
    combine_kernel<<<(N_IT*C3 + 255)/256, 256, 0, stream>>>(Rpart, rspart, emb_item,
                                                            region, Hsrc, J);
    // 4) targets
    tgt_kernel<<<BATCH, 128, 0, stream>>>(item_i, item_j, emb_item, region, bv, TpB, TnB, cpn);
    // 5) q/g GEMMs
    qg_kernel<<<64, 256, 0, stream>>>(TpB, TnB, WqB, WvTB, bq, Qp, Qn, Gp, Gn);
    // 6) batch attention network
    batch_kernel<<<BATCH, 256, 0, stream>>>(user, item_i, Hsrc, WkB, bk,
                                            Qp, Qn, Gp, Gn, cpn, out);
}